// Round 16
// baseline (1274.776 us; speedup 1.0000x reference)
//
#include <hip/hip_runtime.h>
#include <hip/hip_fp16.h>

// ---------------------------------------------------------------------------
// R16 = R15 with NORMAL launch for mlp_tail (hipLaunchCooperativeKernel never
// executed -> out stayed zero; R12 proved 1024x256 @ launch_bounds(256,4) is
// de-facto co-resident: its 10 spin barriers completed and passed refcheck).
// Structure: init_ws + layer0 (R10's known-good) + ONE fused kernel for
// layers 1..10 with 9 internal device barriers. Tail keeps 2-row liveness
// (~45 regs < 64 empirical budget) so no spills (R12 spilled at 4-row).
// ---------------------------------------------------------------------------

#define NBLK 1024
#define NTHR 256
#define BATCHN 1048576
#define NREP 32        // LDS stat replicas (stride 49 odd -> bank bijection)
#define SSTR 49
#define NSLOT 32       // global stat slots
#define SLOTW 48       // floats per slot: [0..23]=sum, [24..47]=sumsq
#define BARSLOT 8      // arrival counter lines per barrier
#define BARPAD 32      // uints per line (128B)
#define NBAR 9         // internal barriers (after layers 1..9)

static_assert(NBLK * NTHR * 4 == BATCHN, "row coverage");

static constexpr int D_[12] = {64, 4, 20, 10, 10, 10, 10, 10, 5, 5, 5, 1};

typedef float floatx4 __attribute__((ext_vector_type(4)));
typedef float floatx2 __attribute__((ext_vector_type(2)));

static constexpr int np_(int d) { return (d + 1) / 2; }
static constexpr int w2offc(int l) {   // float2 offset of layer l (l>=1)
    int o = 0;
    for (int k = 1; k < l; ++k) o += D_[k + 1] * np_(D_[k]);
    return o;
}
static constexpr int boffc(int l) {
    int o = 0;
    for (int k = 0; k < l; ++k) o += D_[k + 1];
    return o;
}
static constexpr int W2TOT = w2offc(11);
static constexpr int BTOT = boffc(11);
static constexpr int GTOT = boffc(10);

__device__ __forceinline__ float fast_tanh(float x) {
    const float e = exp2f(x * 2.8853900817779268f);
    return 1.0f - __fdividef(2.0f, e + 1.0f);
}
__device__ __forceinline__ floatx4 ntld4(const void* p) {
    return __builtin_nontemporal_load((const floatx4*)p);
}
__device__ __forceinline__ floatx2 ntld2(const void* p) {
    return __builtin_nontemporal_load((const floatx2*)p);
}
__device__ __forceinline__ void ntst4(void* p, floatx4 v) {
    __builtin_nontemporal_store(v, (floatx4*)p);
}
__device__ __forceinline__ void ntst2(void* p, floatx2 v) {
    __builtin_nontemporal_store(v, (floatx2*)p);
}

struct Params {
    const float* W[11];
    const float* b[11];
    const float* g[10];
    const float* bt[10];
    float* out;
    float* gstats;   // [10][NSLOT][SLOTW]
    unsigned* bar;   // [NBAR][BARSLOT][BARPAD]
    unsigned* flags; // [NBAR][BARSLOT][BARPAD]
    __half2* hA;
    __half2* hB;
};

// ---- device barrier (index bi), R12-proven ---------------------------------
__device__ __forceinline__ void dev_barrier(const Params& p, int bi, int tid, int bid) {
    __syncthreads();
    if (tid == 0) {
        unsigned* bar = p.bar + (size_t)bi * BARSLOT * BARPAD;
        unsigned* flg = p.flags + (size_t)bi * BARSLOT * BARPAD;
        const int slot = bid & (BARSLOT - 1);
        __hip_atomic_fetch_add(&bar[slot * BARPAD], 1u,
                               __ATOMIC_RELEASE, __HIP_MEMORY_SCOPE_AGENT);
        if (bid == 0) {
            unsigned tot;
            do {
                tot = 0;
                for (int q = 0; q < BARSLOT; ++q)
                    tot += __hip_atomic_load(&bar[q * BARPAD],
                                             __ATOMIC_RELAXED, __HIP_MEMORY_SCOPE_AGENT);
                if (tot < NBLK) __builtin_amdgcn_s_sleep(2);
            } while (tot < NBLK);
            (void)__hip_atomic_load(&bar[0], __ATOMIC_ACQUIRE,
                                    __HIP_MEMORY_SCOPE_AGENT);
            for (int q = 0; q < BARSLOT; ++q)
                __hip_atomic_store(&flg[q * BARPAD], 1u,
                                   __ATOMIC_RELEASE, __HIP_MEMORY_SCOPE_AGENT);
        } else {
            while (__hip_atomic_load(&flg[slot * BARPAD],
                                     __ATOMIC_RELAXED, __HIP_MEMORY_SCOPE_AGENT) == 0u)
                __builtin_amdgcn_s_sleep(2);
            (void)__hip_atomic_load(&flg[slot * BARPAD],
                                    __ATOMIC_ACQUIRE, __HIP_MEMORY_SCOPE_AGENT);
        }
    }
    __syncthreads();
}

// ---- block-end stats deposit ------------------------------------------------
template <int DOUT>
__device__ __forceinline__ void stats_deposit(float* bsum, float* __restrict__ gslots,
                                              int tid, int bid) {
    __syncthreads();
    if (tid < 2 * DOUT) {
        const int idx = (tid < DOUT) ? tid : (24 + (tid - DOUT));
        float v = 0.0f;
        for (int r = 0; r < NREP; ++r) v += bsum[r * SSTR + idx];
        atomicAdd(&gslots[(bid & (NSLOT - 1)) * SLOTW + idx], v);   // device scope
    }
}

// ---- staging ---------------------------------------------------------------
template <int L>
__device__ __forceinline__ void stageW2(const Params& p, float2* lw2, int tid) {
    constexpr int DIN = D_[L], DOUT = D_[L + 1], NPI = np_(DIN), WO = w2offc(L);
    for (int i = tid; i < DOUT * NPI; i += NTHR) {
        const int o = i / NPI, cp = i - o * NPI;
        const float w0 = p.W[L][o * DIN + 2 * cp];
        const float w1 = (2 * cp + 1 < DIN) ? p.W[L][o * DIN + 2 * cp + 1] : 0.0f;
        lw2[WO + i] = make_float2(w0, w1);
    }
}

// ---- fused layer (L=1..9): prologue + 2x 2-row pass + stats + barrier ------
template <int L>
__device__ __forceinline__ void coop_layer(const Params& p,
                                           const __half2* __restrict__ hin,
                                           __half2* __restrict__ hout,
                                           const float2* lw2, const float* lB,
                                           const float* lG, const float* lT,
                                           float* bsum, float* red,
                                           float* lsc, float* lsh,
                                           int tid, int bid) {
    constexpr int DIN = D_[L], DOUT = D_[L + 1];
    constexpr int NPI = np_(DIN), NPO = np_(DOUT);
    constexpr int WO = w2offc(L), BO = boffc(L), GO = boffc(L - 1);
    const float* gsPrev = p.gstats + (size_t)(L - 1) * NSLOT * SLOTW;
    float* gsOut = p.gstats + (size_t)L * NSLOT * SLOTW;

    for (int i = tid; i < NREP * SSTR; i += NTHR) bsum[i] = 0.0f;
    if (tid < 2 * DIN) red[tid] = 0.0f;
    __syncthreads();
    {   // prologue: reduce prev layer's 32 slots
        const int f = tid & 63, c = tid >> 6;   // c in 0..3
        if (f < 2 * DIN) {
            const int idx = (f < DIN) ? f : (24 + (f - DIN));
            float v = 0.0f;
#pragma unroll
            for (int q = 0; q < 8; ++q)
                v += gsPrev[(c * 8 + q) * SLOTW + idx];
            atomicAdd(&red[f], v);
        }
    }
    __syncthreads();
    if (tid < DIN) {
        constexpr float inv = 1.0f / (float)BATCHN;
        const float m = red[tid] * inv;
        const float var = fmaxf(red[DIN + tid] * inv - m * m, 0.0f);
        const float sc = lG[GO + tid] * rsqrtf(var + 1e-5f);
        lsc[tid] = sc;
        lsh[tid] = lT[GO + tid] - m * sc;
    }
    __syncthreads();

    const int e = bid * NTHR + tid;   // rows 4e..4e+3, two 2-row passes
    const int rep = (tid & 31) * SSTR;
#pragma unroll 1
    for (int r2 = 0; r2 < 2; ++r2) {
        const int row0 = 4 * e + 2 * r2;
        __half2 a2[2][NPI];
#pragma unroll
        for (int cp = 0; cp < NPI; ++cp) {
            const floatx2 pl = ntld2((const float*)(hin + (size_t)cp * BATCHN) + row0);
            const __half2* h2 = (const __half2*)&pl;
#pragma unroll
            for (int r = 0; r < 2; ++r) {
                const float t0 = fast_tanh(fmaf(__low2float(h2[r]), lsc[2 * cp], lsh[2 * cp]));
                const float t1 = (2 * cp + 1 < DIN)
                    ? fast_tanh(fmaf(__high2float(h2[r]), lsc[2 * cp + 1], lsh[2 * cp + 1]))
                    : 0.0f;
                a2[r][cp] = __floats2half2_rn(t0, t1);
            }
        }
#pragma unroll
        for (int op = 0; op < NPO; ++op) {
            const int o0 = 2 * op, o1 = o0 + 1;
            float a0[2], a1[2];
#pragma unroll
            for (int r = 0; r < 2; ++r) {
                a0[r] = lB[BO + o0];
                a1[r] = (o1 < DOUT) ? lB[BO + o1] : 0.0f;
            }
#pragma unroll
            for (int cp = 0; cp < NPI; ++cp) {
                const float2 w0 = lw2[WO + o0 * NPI + cp];
                const float2 w1 = (o1 < DOUT) ? lw2[WO + o1 * NPI + cp] : make_float2(0.f, 0.f);
#pragma unroll
                for (int r = 0; r < 2; ++r) {
                    const float x0 = __low2float(a2[r][cp]);
                    const float x1 = __high2float(a2[r][cp]);
                    a0[r] = fmaf(w0.x, x0, fmaf(w0.y, x1, a0[r]));
                    a1[r] = fmaf(w1.x, x0, fmaf(w1.y, x1, a1[r]));
                }
            }
            atomicAdd(&bsum[rep + o0], a0[0] + a0[1]);
            atomicAdd(&bsum[rep + 24 + o0], fmaf(a0[0], a0[0], a0[1] * a0[1]));
            if (o1 < DOUT) {
                atomicAdd(&bsum[rep + o1], a1[0] + a1[1]);
                atomicAdd(&bsum[rep + 24 + o1], fmaf(a1[0], a1[0], a1[1] * a1[1]));
            }
            floatx2 st;
            __half2* sp = (__half2*)&st;
#pragma unroll
            for (int r = 0; r < 2; ++r)
                sp[r] = __floats2half2_rn(a0[r], (o1 < DOUT) ? a1[r] : 0.0f);
            ntst2((float*)(hout + (size_t)op * BATCHN) + row0, st);
        }
    }
    stats_deposit<DOUT>(bsum, gsOut, tid, bid);
    dev_barrier(p, L - 1, tid, bid);
}

// ---- fused tail kernel: layers 1..10 (NORMAL launch, de-facto co-resident) -
__global__ void __launch_bounds__(NTHR, 4) mlp_tail(Params p) {
    __shared__ __align__(8) float2 lw2[W2TOT];
    __shared__ float lB[BTOT], lG[GTOT], lT[GTOT];
    __shared__ float bsum[NREP * SSTR];
    __shared__ float red[40], lsc[20], lsh[20];

    const int tid = threadIdx.x, bid = blockIdx.x;

    stageW2<1>(p, lw2, tid);  stageW2<2>(p, lw2, tid);  stageW2<3>(p, lw2, tid);
    stageW2<4>(p, lw2, tid);  stageW2<5>(p, lw2, tid);  stageW2<6>(p, lw2, tid);
    stageW2<7>(p, lw2, tid);  stageW2<8>(p, lw2, tid);  stageW2<9>(p, lw2, tid);
    stageW2<10>(p, lw2, tid);
    for (int l = 0; l < 11; ++l)
        if (tid < D_[l + 1]) lB[boffc(l) + tid] = p.b[l][tid];
    for (int l = 0; l < 10; ++l)
        if (tid < D_[l + 1]) {
            lG[boffc(l) + tid] = p.g[l][tid];
            lT[boffc(l) + tid] = p.bt[l][tid];
        }
    __syncthreads();

    coop_layer<1>(p, p.hA, p.hB, lw2, lB, lG, lT, bsum, red, lsc, lsh, tid, bid);
    coop_layer<2>(p, p.hB, p.hA, lw2, lB, lG, lT, bsum, red, lsc, lsh, tid, bid);
    coop_layer<3>(p, p.hA, p.hB, lw2, lB, lG, lT, bsum, red, lsc, lsh, tid, bid);
    coop_layer<4>(p, p.hB, p.hA, lw2, lB, lG, lT, bsum, red, lsc, lsh, tid, bid);
    coop_layer<5>(p, p.hA, p.hB, lw2, lB, lG, lT, bsum, red, lsc, lsh, tid, bid);
    coop_layer<6>(p, p.hB, p.hA, lw2, lB, lG, lT, bsum, red, lsc, lsh, tid, bid);
    coop_layer<7>(p, p.hA, p.hB, lw2, lB, lG, lT, bsum, red, lsc, lsh, tid, bid);
    coop_layer<8>(p, p.hB, p.hA, lw2, lB, lG, lT, bsum, red, lsc, lsh, tid, bid);
    coop_layer<9>(p, p.hA, p.hB, lw2, lB, lG, lT, bsum, red, lsc, lsh, tid, bid);

    // ---- layer 10: BN_9+tanh, linear 5->1, sigmoid -> out ----
    {
        constexpr int WO = w2offc(10), BO = boffc(10), GO = boffc(9);
        const float* gsPrev = p.gstats + (size_t)9 * NSLOT * SLOTW;
        if (tid < 10) red[tid] = 0.0f;
        __syncthreads();
        {
            const int f = tid & 63, c = tid >> 6;
            if (f < 10) {
                const int idx = (f < 5) ? f : (24 + (f - 5));
                float v = 0.0f;
#pragma unroll
                for (int q = 0; q < 8; ++q)
                    v += gsPrev[(c * 8 + q) * SLOTW + idx];
                atomicAdd(&red[f], v);
            }
        }
        __syncthreads();
        if (tid < 5) {
            constexpr float inv = 1.0f / (float)BATCHN;
            const float m = red[tid] * inv;
            const float var = fmaxf(red[5 + tid] * inv - m * m, 0.0f);
            const float sc = lG[GO + tid] * rsqrtf(var + 1e-5f);
            lsc[tid] = sc;
            lsh[tid] = lT[GO + tid] - m * sc;
        }
        if (tid == 5) { lsc[5] = 0.0f; lsh[5] = 0.0f; }
        __syncthreads();

        const int e = bid * NTHR + tid;
        const float lb0 = lB[BO];
#pragma unroll 1
        for (int r2 = 0; r2 < 2; ++r2) {
            const int row0 = 4 * e + 2 * r2;
            float a[2] = {lb0, lb0};
#pragma unroll
            for (int cp = 0; cp < 3; ++cp) {
                const float2 w = lw2[WO + cp];
                const floatx2 pl = ntld2((const float*)(p.hB + (size_t)cp * BATCHN) + row0);
                const __half2* h2 = (const __half2*)&pl;
#pragma unroll
                for (int r = 0; r < 2; ++r) {
                    const float t0 = fast_tanh(fmaf(__low2float(h2[r]), lsc[2 * cp], lsh[2 * cp]));
                    const float t1 = fast_tanh(fmaf(__high2float(h2[r]), lsc[2 * cp + 1], lsh[2 * cp + 1]));
                    a[r] = fmaf(w.x, t0, fmaf(w.y, t1, a[r]));
                }
            }
            floatx2 ov;
#pragma unroll
            for (int r = 0; r < 2; ++r) {
                const float e2 = exp2f(a[r] * -1.4426950408889634f);
                ov[r] = __fdividef(1.0f, 1.0f + e2);
            }
            ntst2(p.out + row0, ov);
        }
    }
}

// ---- layer 0 (normal launch): R10's known-good kernel ----------------------
__global__ void __launch_bounds__(NTHR) layer0(
        const float* __restrict__ x, __half2* __restrict__ hout,
        const float* __restrict__ W, const float* __restrict__ b,
        float* __restrict__ gslots) {
    __shared__ float bsum[NREP * SSTR];
    __shared__ __half2 hs[2][1024];
    const int tid = threadIdx.x, bid = blockIdx.x;
    const int wv = tid >> 6, lane = tid & 63, grp = lane >> 2, sub = lane & 3;
    for (int i = tid; i < NREP * SSTR; i += NTHR) bsum[i] = 0.0f;

    floatx4 w[4][4];
    float bb[4];
#pragma unroll
    for (int o = 0; o < 4; ++o) {
        bb[o] = b[o];
#pragma unroll
        for (int q = 0; q < 4; ++q)
            w[o][q] = *(const floatx4*)(W + o * 64 + sub * 16 + q * 4);
    }
    float sl[4] = {0.f, 0.f, 0.f, 0.f}, ql[4] = {0.f, 0.f, 0.f, 0.f};
    __syncthreads();

    const int rbase = bid * 1024;
#pragma unroll
    for (int pass = 0; pass < 16; ++pass) {
        const int lrow = wv * 16 + grp + pass * 64;
        const float* xr = x + (size_t)(rbase + lrow) * 64 + sub * 16;
        float par[4] = {0.f, 0.f, 0.f, 0.f};
#pragma unroll
        for (int q = 0; q < 4; ++q) {
            const floatx4 xv = ntld4(xr + q * 4);
#pragma unroll
            for (int o = 0; o < 4; ++o)
                par[o] = fmaf(w[o][q].x, xv.x, fmaf(w[o][q].y, xv.y,
                          fmaf(w[o][q].z, xv.z, fmaf(w[o][q].w, xv.w, par[o]))));
        }
#pragma unroll
        for (int o = 0; o < 4; ++o) {
            par[o] += __shfl_xor(par[o], 1, 64);
            par[o] += __shfl_xor(par[o], 2, 64);
        }
        if (sub == 0) {
            float hv[4];
#pragma unroll
            for (int o = 0; o < 4; ++o) {
                hv[o] = par[o] + bb[o];
                sl[o] += hv[o];
                ql[o] = fmaf(hv[o], hv[o], ql[o]);
            }
            hs[0][lrow] = __floats2half2_rn(hv[0], hv[1]);
            hs[1][lrow] = __floats2half2_rn(hv[2], hv[3]);
        }
    }
    if (sub == 0) {
        const int rep = (tid & 31) * SSTR;
#pragma unroll
        for (int o = 0; o < 4; ++o) {
            atomicAdd(&bsum[rep + o], sl[o]);
            atomicAdd(&bsum[rep + 24 + o], ql[o]);
        }
    }
    __syncthreads();   // hs complete
    ntst4((float*)hout + rbase + tid * 4, ((const floatx4*)hs[0])[tid]);
    ntst4((float*)(hout + BATCHN) + rbase + tid * 4, ((const floatx4*)hs[1])[tid]);
    stats_deposit<4>(bsum, gslots, tid, bid);
}

// zero all gstats + barrier state each call (ws not re-poisoned between replays)
__global__ void init_ws(float* __restrict__ gstats, unsigned* __restrict__ bar,
                        unsigned* __restrict__ flags) {
    const int i = threadIdx.x + blockIdx.x * blockDim.x;
    if (i < 10 * NSLOT * SLOTW) gstats[i] = 0.0f;
    if (i < NBAR * BARSLOT * BARPAD) { bar[i] = 0u; flags[i] = 0u; }
}

extern "C" void kernel_launch(void* const* d_in, const int* in_sizes, int n_in,
                              void* d_out, int out_size, void* d_ws, size_t ws_size,
                              hipStream_t stream) {
    Params p;
    const float* x = (const float*)d_in[0];
    int k = 1;
    for (int l = 0; l < 11; ++l) {
        p.W[l] = (const float*)d_in[k++];
        p.b[l] = (const float*)d_in[k++];
        if (l < 10) {
            p.g[l] = (const float*)d_in[k++];
            p.bt[l] = (const float*)d_in[k++];
        }
    }
    p.out = (float*)d_out;

    // ws layout (bytes):
    //   gstats @ 0      : 10*32*48*4 = 61440
    //   bar    @ 61440  : 9*8*32*4   = 9216
    //   flags  @ 70656  : 9*8*32*4   = 9216
    //   hA     @ 131072 : 5 planes x 4MB
    //   hB     @ 131072+20971520 : 10 planes x 4MB
    char* ws = (char*)d_ws;
    p.gstats = (float*)ws;
    p.bar    = (unsigned*)(ws + 61440);
    p.flags  = (unsigned*)(ws + 70656);
    p.hA     = (__half2*)(ws + 131072);
    p.hB     = (__half2*)(ws + 131072 + 20971520);

    init_ws<<<dim3(64), dim3(256), 0, stream>>>(p.gstats, p.bar, p.flags);
    layer0<<<dim3(NBLK), dim3(NTHR), 0, stream>>>(x, p.hA, p.W[0], p.b[0], p.gstats);
    mlp_tail<<<dim3(NBLK), dim3(NTHR), 0, stream>>>(p);
}

// Round 17
// 399.002 us; speedup vs baseline: 3.1949x; 3.1949x over previous
//
#include <hip/hip_runtime.h>
#include <hip/hip_fp16.h>

// ---------------------------------------------------------------------------
// R17 = R10 verbatim (the 398us champion). Final structure:
// 12 graph-captured launches; kernel boundary = the global sync each of the
// 10 training-mode BatchNorms requires. Per-layer: column-plane f16
// intermediates (SoA, float4/lane NT I/O), LDS stat replicas -> 64 padded
// global slots -> consumer-prologue reduce (no atomic counters, no spin).
// Established by R1-R16 elimination:
//  * persistent/fused kernels ALWAYS spill on this toolchain (7 attempts:
//    R1-4 R12 R13 R16; VGPR budget tracks occupancy request, frame spills
//    to scratch at 300MB-1GB traffic).
//  * boundary cost ~25us/kernel is invariant to dispatch shape (R11 worse),
//    cache mode (R14 worse), barrier impl (R4/R7 neutral), NT hints (R10
//    -41us, kept). 11 boundaries x ~25us + ~75us layer0 + tails = ~398us.
// ---------------------------------------------------------------------------

#define NTHR 256
#define BATCHN 1048576
#define L0BLK 1024     // layer0: 1024 rows/block
#define MIDBLK 1024    // mid layers: 4 rows/thread
#define NREP 32        // LDS stat replicas (stride 49 odd -> bank bijection)
#define SSTR 49
#define NSLOT 64       // global stat slots
#define SLOTW 48       // floats per slot: [0..23]=sum, [24..47]=sumsq

static_assert(L0BLK * 1024 == BATCHN, "layer0 row coverage");
static_assert(MIDBLK * NTHR * 4 == BATCHN, "mid row coverage");

static constexpr int D_[12] = {64, 4, 20, 10, 10, 10, 10, 10, 5, 5, 5, 1};

typedef float floatx4 __attribute__((ext_vector_type(4)));

__device__ __forceinline__ float fast_tanh(float x) {
    const float e = exp2f(x * 2.8853900817779268f);
    return 1.0f - __fdividef(2.0f, e + 1.0f);
}

__device__ __forceinline__ floatx4 ntld4(const void* p) {
    return __builtin_nontemporal_load((const floatx4*)p);
}
__device__ __forceinline__ void ntst4(void* p, floatx4 v) {
    __builtin_nontemporal_store(v, (floatx4*)p);
}

// ---- block-end stats deposit: LDS replicas -> one global atomic per block --
template <int DOUT>
__device__ __forceinline__ void stats_deposit(float* bsum, float* __restrict__ gslots,
                                              int tid, int bid) {
    __syncthreads();   // all LDS stat atomics done
    if (tid < 2 * DOUT) {
        const int idx = (tid < DOUT) ? tid : (24 + (tid - DOUT));
        float v = 0.0f;
        for (int r = 0; r < NREP; ++r) v += bsum[r * SSTR + idx];
        atomicAdd(&gslots[(bid & (NSLOT - 1)) * SLOTW + idx], v);   // device scope
    }
}

// ---- prologue: reduce previous layer's slots -> lsc/lsh (per block) --------
// thread (f = tid&63, c = tid>>6): register-sum 16 slots, one LDS atomic.
template <int DIN>
__device__ __forceinline__ void slots_to_scsh(const float* __restrict__ gsPrev,
                                              const float* __restrict__ gPrev,
                                              const float* __restrict__ btPrev,
                                              float* red, float* lsc, float* lsh,
                                              int tid) {
    constexpr int NF = 2 * DIN;
    const int f = tid & 63, c = tid >> 6;
    if (f < NF) {
        const int idx = (f < DIN) ? f : (24 + (f - DIN));
        float v = 0.0f;
#pragma unroll
        for (int q = 0; q < 16; ++q)
            v += gsPrev[(c * 16 + q) * SLOTW + idx];
        atomicAdd(&red[f], v);
    }
    __syncthreads();
    if (tid < DIN) {
        constexpr float inv = 1.0f / (float)BATCHN;
        const float m = red[tid] * inv;
        const float var = fmaxf(red[DIN + tid] * inv - m * m, 0.0f);
        const float sc = gPrev[tid] * rsqrtf(var + 1e-5f);
        lsc[tid] = sc;
        lsh[tid] = btPrev[tid] - m * sc;
    }
    __syncthreads();
}

// ---- layer 0: x(64) -> h0 (4 features = 2 planes) --------------------------
// 4 lanes/row, 16 cols/lane; 2-level shfl reduce; LDS gather -> bulk store.
__global__ void __launch_bounds__(NTHR) layer0(
        const float* __restrict__ x, __half2* __restrict__ hout,
        const float* __restrict__ W, const float* __restrict__ b,
        float* __restrict__ gslots, float* __restrict__ gsNext) {
    __shared__ float bsum[NREP * SSTR];
    __shared__ __half2 hs[2][1024];
    const int tid = threadIdx.x, bid = blockIdx.x;
    const int wv = tid >> 6, lane = tid & 63, grp = lane >> 2, sub = lane & 3;
    for (int i = tid; i < NREP * SSTR; i += NTHR) bsum[i] = 0.0f;
    if (bid == 0)   // zero next layer's slots (ordered by kernel boundary)
        for (int i = tid; i < NSLOT * SLOTW; i += NTHR) gsNext[i] = 0.0f;

    floatx4 w[4][4];
    float bb[4];
#pragma unroll
    for (int o = 0; o < 4; ++o) {
        bb[o] = b[o];
#pragma unroll
        for (int q = 0; q < 4; ++q)
            w[o][q] = *(const floatx4*)(W + o * 64 + sub * 16 + q * 4);
    }
    float sl[4] = {0.f, 0.f, 0.f, 0.f}, ql[4] = {0.f, 0.f, 0.f, 0.f};
    __syncthreads();

    const int rbase = bid * 1024;
#pragma unroll
    for (int pass = 0; pass < 16; ++pass) {
        const int lrow = wv * 16 + grp + pass * 64;
        const float* xr = x + (size_t)(rbase + lrow) * 64 + sub * 16;
        float par[4] = {0.f, 0.f, 0.f, 0.f};
#pragma unroll
        for (int q = 0; q < 4; ++q) {
            const floatx4 xv = ntld4(xr + q * 4);
#pragma unroll
            for (int o = 0; o < 4; ++o)
                par[o] = fmaf(w[o][q].x, xv.x, fmaf(w[o][q].y, xv.y,
                          fmaf(w[o][q].z, xv.z, fmaf(w[o][q].w, xv.w, par[o]))));
        }
#pragma unroll
        for (int o = 0; o < 4; ++o) {
            par[o] += __shfl_xor(par[o], 1, 64);
            par[o] += __shfl_xor(par[o], 2, 64);
        }
        if (sub == 0) {
            float hv[4];
#pragma unroll
            for (int o = 0; o < 4; ++o) {
                hv[o] = par[o] + bb[o];
                sl[o] += hv[o];
                ql[o] = fmaf(hv[o], hv[o], ql[o]);
            }
            hs[0][lrow] = __floats2half2_rn(hv[0], hv[1]);
            hs[1][lrow] = __floats2half2_rn(hv[2], hv[3]);
        }
    }
    if (sub == 0) {
        const int rep = (tid & 31) * SSTR;
#pragma unroll
        for (int o = 0; o < 4; ++o) {
            atomicAdd(&bsum[rep + o], sl[o]);
            atomicAdd(&bsum[rep + 24 + o], ql[o]);
        }
    }
    __syncthreads();   // hs complete
    ntst4((float*)hout + rbase + tid * 4, ((const floatx4*)hs[0])[tid]);
    ntst4((float*)(hout + BATCHN) + rbase + tid * 4, ((const floatx4*)hs[1])[tid]);
    stats_deposit<4>(bsum, gslots, tid, bid);
}

// ---- layers 1..9: prologue BN params, BN+tanh fused, linear, emit planes ---
template <int L>
__global__ void __launch_bounds__(NTHR) layer_mid(
        const __half2* __restrict__ hin, __half2* __restrict__ hout,
        const float* __restrict__ W, const float* __restrict__ b,
        const float* __restrict__ gPrev, const float* __restrict__ btPrev,
        const float* __restrict__ gsPrev, float* __restrict__ gsOut,
        float* __restrict__ gsNext) {
    constexpr int DIN = D_[L], DOUT = D_[L + 1];
    constexpr int NPI = (DIN + 1) / 2, NPO = (DOUT + 1) / 2;
    __shared__ float2 lw[DOUT * NPI];
    __shared__ float lb[DOUT], lsc[DIN], lsh[DIN];
    __shared__ float red[2 * DIN];
    __shared__ float bsum[NREP * SSTR];
    const int tid = threadIdx.x, bid = blockIdx.x;
    for (int i = tid; i < DOUT * NPI; i += NTHR) {
        const int o = i / NPI, cp = i - o * NPI;
        const float w0 = W[o * DIN + 2 * cp];
        const float w1 = (2 * cp + 1 < DIN) ? W[o * DIN + 2 * cp + 1] : 0.0f;
        lw[i] = make_float2(w0, w1);
    }
    if (tid < DOUT) lb[tid] = b[tid];
    if (tid < 2 * DIN) red[tid] = 0.0f;
    for (int i = tid; i < NREP * SSTR; i += NTHR) bsum[i] = 0.0f;
    if (gsNext && bid == 0)
        for (int i = tid; i < NSLOT * SLOTW; i += NTHR) gsNext[i] = 0.0f;
    __syncthreads();
    slots_to_scsh<DIN>(gsPrev, gPrev, btPrev, red, lsc, lsh, tid);

    const int ei = bid * NTHR + tid;   // 4-row group index; rows 4ei..4ei+3

    // load planes (float4 = 4 rows) non-temporally, BN+tanh, repack
    __half2 a2[4][NPI];
#pragma unroll
    for (int cp = 0; cp < NPI; ++cp) {
        const floatx4 pl = ntld4((const float*)(hin + (size_t)cp * BATCHN) + (size_t)ei * 4);
        const __half2* h4 = (const __half2*)&pl;
#pragma unroll
        for (int r = 0; r < 4; ++r) {
            const float t0 = fast_tanh(fmaf(__low2float(h4[r]), lsc[2 * cp], lsh[2 * cp]));
            const float t1 = (2 * cp + 1 < DIN)
                ? fast_tanh(fmaf(__high2float(h4[r]), lsc[2 * cp + 1], lsh[2 * cp + 1]))
                : 0.0f;
            a2[r][cp] = __floats2half2_rn(t0, t1);
        }
    }

    const int rep = (tid & 31) * SSTR;
#pragma unroll
    for (int op = 0; op < NPO; ++op) {
        const int o0 = 2 * op, o1 = o0 + 1;
        float a0[4], a1[4];
#pragma unroll
        for (int r = 0; r < 4; ++r) {
            a0[r] = lb[o0];
            a1[r] = (o1 < DOUT) ? lb[o1] : 0.0f;
        }
#pragma unroll
        for (int cp = 0; cp < NPI; ++cp) {
            const float2 w0 = lw[o0 * NPI + cp];
            const float2 w1 = (o1 < DOUT) ? lw[o1 * NPI + cp] : make_float2(0.0f, 0.0f);
#pragma unroll
            for (int r = 0; r < 4; ++r) {
                const float x0 = __low2float(a2[r][cp]);
                const float x1 = __high2float(a2[r][cp]);
                a0[r] = fmaf(w0.x, x0, fmaf(w0.y, x1, a0[r]));
                a1[r] = fmaf(w1.x, x0, fmaf(w1.y, x1, a1[r]));
            }
        }
        {
            const float s0 = (a0[0] + a0[1]) + (a0[2] + a0[3]);
            const float q0 = fmaf(a0[0], a0[0], fmaf(a0[1], a0[1],
                              fmaf(a0[2], a0[2], a0[3] * a0[3])));
            atomicAdd(&bsum[rep + o0], s0);
            atomicAdd(&bsum[rep + 24 + o0], q0);
            if (o1 < DOUT) {
                const float s1 = (a1[0] + a1[1]) + (a1[2] + a1[3]);
                const float q1 = fmaf(a1[0], a1[0], fmaf(a1[1], a1[1],
                                  fmaf(a1[2], a1[2], a1[3] * a1[3])));
                atomicAdd(&bsum[rep + o1], s1);
                atomicAdd(&bsum[rep + 24 + o1], q1);
            }
        }
        floatx4 st;
        __half2* sp = (__half2*)&st;
#pragma unroll
        for (int r = 0; r < 4; ++r)
            sp[r] = __floats2half2_rn(a0[r], (o1 < DOUT) ? a1[r] : 0.0f);
        ntst4((float*)(hout + (size_t)op * BATCHN) + (size_t)ei * 4, st);
    }
    stats_deposit<DOUT>(bsum, gsOut, tid, bid);
}

// ---- layer 10: prologue BN_9, tanh, linear 5->1, sigmoid -> out(f32) -------
__global__ void __launch_bounds__(NTHR) layer10(
        const __half2* __restrict__ hin, float* __restrict__ out,
        const float* __restrict__ W, const float* __restrict__ b,
        const float* __restrict__ gPrev, const float* __restrict__ btPrev,
        const float* __restrict__ gsPrev) {
    __shared__ float lw[6], lsc[6], lsh[6];
    __shared__ float red[10];
    __shared__ float lb0;
    const int tid = threadIdx.x, bid = blockIdx.x;
    if (tid < 5) lw[tid] = W[tid];
    if (tid == 5) { lw[5] = 0.0f; lsc[5] = 0.0f; lsh[5] = 0.0f; }
    if (tid == 0) lb0 = b[0];
    if (tid < 10) red[tid] = 0.0f;
    __syncthreads();
    slots_to_scsh<5>(gsPrev, gPrev, btPrev, red, lsc, lsh, tid);

    const int ei = bid * NTHR + tid;
    float a[4] = {lb0, lb0, lb0, lb0};
#pragma unroll
    for (int cp = 0; cp < 3; ++cp) {
        const floatx4 pl = ntld4((const float*)(hin + (size_t)cp * BATCHN) + (size_t)ei * 4);
        const __half2* h4 = (const __half2*)&pl;
#pragma unroll
        for (int r = 0; r < 4; ++r) {
            const float t0 = fast_tanh(fmaf(__low2float(h4[r]), lsc[2 * cp], lsh[2 * cp]));
            const float t1 = fast_tanh(fmaf(__high2float(h4[r]), lsc[2 * cp + 1], lsh[2 * cp + 1]));
            a[r] = fmaf(lw[2 * cp], t0, fmaf(lw[2 * cp + 1], t1, a[r]));
        }
    }
    floatx4 ov;
#pragma unroll
    for (int r = 0; r < 4; ++r) {
        const float e = exp2f(a[r] * -1.4426950408889634f);
        ov[r] = __fdividef(1.0f, 1.0f + e);
    }
    ntst4(out + (size_t)ei * 4, ov);
}

// zero GS(0) only; GS(L+1) is zeroed by kernel L's block 0.
__global__ void init_ws(float* __restrict__ gs0) {
    const int i = threadIdx.x + blockIdx.x * blockDim.x;
    if (i < NSLOT * SLOTW) gs0[i] = 0.0f;
}

extern "C" void kernel_launch(void* const* d_in, const int* in_sizes, int n_in,
                              void* d_out, int out_size, void* d_ws, size_t ws_size,
                              hipStream_t stream) {
    const float *W[11], *b[11], *g[10], *bt[10];
    const float* x = (const float*)d_in[0];
    int k = 1;
    for (int l = 0; l < 11; ++l) {
        W[l] = (const float*)d_in[k++];
        b[l] = (const float*)d_in[k++];
        if (l < 10) {
            g[l] = (const float*)d_in[k++];
            bt[l] = (const float*)d_in[k++];
        }
    }
    float* out = (float*)d_out;

    // ws layout (bytes):
    //   gstats @ 0        : 10*64*48*4 = 122880
    //   hA     @ 131072   : 5 planes x 4MB  (h0:2, h2/h4/h6:5, h8:3)
    //   hB     @ 21102592 : 10 planes x 4MB (h1:10, h3/h5/h7:5, h9:3)
    char* ws = (char*)d_ws;
    float*   gstats = (float*)ws;
    __half2* hA     = (__half2*)(ws + 131072);
    __half2* hB     = (__half2*)(ws + 131072 + 20971520);

    auto GS = [&](int L) { return gstats + (size_t)L * NSLOT * SLOTW; };

    init_ws<<<dim3(12), dim3(NTHR), 0, stream>>>(GS(0));
    layer0<<<dim3(L0BLK), dim3(NTHR), 0, stream>>>(x, hA, W[0], b[0], GS(0), GS(1));
    layer_mid<1><<<dim3(MIDBLK), dim3(NTHR), 0, stream>>>(hA, hB, W[1], b[1],
                                                          g[0], bt[0], GS(0), GS(1), GS(2));
    layer_mid<2><<<dim3(MIDBLK), dim3(NTHR), 0, stream>>>(hB, hA, W[2], b[2],
                                                          g[1], bt[1], GS(1), GS(2), GS(3));
    layer_mid<3><<<dim3(MIDBLK), dim3(NTHR), 0, stream>>>(hA, hB, W[3], b[3],
                                                          g[2], bt[2], GS(2), GS(3), GS(4));
    layer_mid<4><<<dim3(MIDBLK), dim3(NTHR), 0, stream>>>(hB, hA, W[4], b[4],
                                                          g[3], bt[3], GS(3), GS(4), GS(5));
    layer_mid<5><<<dim3(MIDBLK), dim3(NTHR), 0, stream>>>(hA, hB, W[5], b[5],
                                                          g[4], bt[4], GS(4), GS(5), GS(6));
    layer_mid<6><<<dim3(MIDBLK), dim3(NTHR), 0, stream>>>(hB, hA, W[6], b[6],
                                                          g[5], bt[5], GS(5), GS(6), GS(7));
    layer_mid<7><<<dim3(MIDBLK), dim3(NTHR), 0, stream>>>(hA, hB, W[7], b[7],
                                                          g[6], bt[6], GS(6), GS(7), GS(8));
    layer_mid<8><<<dim3(MIDBLK), dim3(NTHR), 0, stream>>>(hB, hA, W[8], b[8],
                                                          g[7], bt[7], GS(7), GS(8), GS(9));
    layer_mid<9><<<dim3(MIDBLK), dim3(NTHR), 0, stream>>>(hA, hB, W[9], b[9],
                                                          g[8], bt[8], GS(8), GS(9), nullptr);
    layer10<<<dim3(MIDBLK), dim3(NTHR), 0, stream>>>(hB, out, W[10], b[10],
                                                     g[9], bt[9], GS(9));
}